// Round 1
// baseline (17061.789 us; speedup 1.0000x reference)
//
#include <hip/hip_runtime.h>
#include <math.h>

// GPT-2 small forward, fp32. B=2 T=1024 C=768 H=12 D=64 L=12 V=50257.
#define CDIM 768
#define HEADS 12
#define DHEAD 64
#define LAYERS 12
#define TLEN 1024
#define BSZ 2
#define MROWS (BSZ * TLEN)   // 2048
#define NV 50257

// ---------------------------------------------------------------- embed ----
__global__ __launch_bounds__(256) void embed_kernel(
    const int* __restrict__ idx, const float* __restrict__ wte,
    const float* __restrict__ wpe, float* __restrict__ x)
{
    int i = blockIdx.x * 256 + threadIdx.x;        // over MROWS*C/4 float4s
    int total = MROWS * CDIM / 4;
    if (i >= total) return;
    int row = i / (CDIM / 4);
    int c4  = i % (CDIM / 4);
    int t   = row % TLEN;
    int tok = idx[row];
    float4 a = ((const float4*)(wte + (size_t)tok * CDIM))[c4];
    float4 b = ((const float4*)(wpe + (size_t)t   * CDIM))[c4];
    float4 o;
    o.x = a.x + b.x; o.y = a.y + b.y; o.z = a.z + b.z; o.w = a.w + b.w;
    ((float4*)(x + (size_t)row * CDIM))[c4] = o;
}

// ------------------------------------------------------------ layernorm ----
// one block (256 threads) per row; C=768 -> 3 elements/thread
__global__ __launch_bounds__(256) void layernorm_kernel(
    const float* __restrict__ in, const float* __restrict__ w,
    const float* __restrict__ b, float* __restrict__ out)
{
    int row = blockIdx.x;
    int tid = threadIdx.x;
    const float* xr = in + (size_t)row * CDIM;
    float v0 = xr[tid], v1 = xr[tid + 256], v2 = xr[tid + 512];
    float s  = v0 + v1 + v2;
    float ss = v0 * v0 + v1 * v1 + v2 * v2;
    #pragma unroll
    for (int o = 1; o < 64; o <<= 1) {
        s  += __shfl_xor(s,  o);
        ss += __shfl_xor(ss, o);
    }
    __shared__ float red[10];
    int wave = tid >> 6, lane = tid & 63;
    if (lane == 0) { red[wave] = s; red[4 + wave] = ss; }
    __syncthreads();
    if (tid == 0) {
        float S  = red[0] + red[1] + red[2] + red[3];
        float SS = red[4] + red[5] + red[6] + red[7];
        float mu  = S / CDIM;
        float var = SS / CDIM - mu * mu;
        red[8] = mu;
        red[9] = rsqrtf(var + 1e-5f);
    }
    __syncthreads();
    float mu = red[8], rstd = red[9];
    float* orow = out + (size_t)row * CDIM;
    orow[tid]       = (v0 - mu) * rstd * w[tid]       + b[tid];
    orow[tid + 256] = (v1 - mu) * rstd * w[tid + 256] + b[tid + 256];
    orow[tid + 512] = (v2 - mu) * rstd * w[tid + 512] + b[tid + 512];
}

// ----------------------------------------------------------------- gemm ----
// out[M,N] = A[M,K] @ B[K,N] (+bias[N]) (gelu?) (+resid[M,N])
// 64x64 tile, BK=16, 256 threads, 4x4 micro-tile per thread.
#define BM 64
#define BN 64
#define BK 16
__global__ __launch_bounds__(256) void gemm_kernel(
    const float* __restrict__ A, const float* __restrict__ Bmat,
    const float* __restrict__ bias, const float* __restrict__ resid,
    float* __restrict__ out, int Mdim, int Ndim, int Kdim, int fuse_gelu)
{
    __shared__ float As[BM][BK + 1];   // pad -> conflict-free column reads
    __shared__ float Bs[BK][BN + 4];
    int tid = threadIdx.x;
    int n0 = blockIdx.x * BN, m0 = blockIdx.y * BM;
    int tx = tid % 16, ty = tid / 16;

    int a_row = tid / 4;          // 0..63
    int a_col = (tid % 4) * 4;    // 0,4,8,12
    int b_row = tid / 16;         // 0..15
    int b_col = (tid % 16) * 4;   // 0..60
    int gn = n0 + b_col;
    bool n_vec = ((Ndim & 3) == 0);

    float acc[4][4] = {};
    for (int k0 = 0; k0 < Kdim; k0 += BK) {
        float4 av = *(const float4*)(A + (size_t)(m0 + a_row) * Kdim + k0 + a_col);
        As[a_row][a_col + 0] = av.x;
        As[a_row][a_col + 1] = av.y;
        As[a_row][a_col + 2] = av.z;
        As[a_row][a_col + 3] = av.w;

        const float* Brow = Bmat + (size_t)(k0 + b_row) * Ndim;
        if (n_vec && gn + 4 <= Ndim) {
            float4 bv = *(const float4*)(Brow + gn);
            Bs[b_row][b_col + 0] = bv.x;
            Bs[b_row][b_col + 1] = bv.y;
            Bs[b_row][b_col + 2] = bv.z;
            Bs[b_row][b_col + 3] = bv.w;
        } else {
            #pragma unroll
            for (int j = 0; j < 4; ++j)
                Bs[b_row][b_col + j] = (gn + j < Ndim) ? Brow[gn + j] : 0.f;
        }
        __syncthreads();
        #pragma unroll
        for (int kk = 0; kk < BK; ++kk) {
            float a0 = As[ty * 4 + 0][kk];
            float a1 = As[ty * 4 + 1][kk];
            float a2 = As[ty * 4 + 2][kk];
            float a3 = As[ty * 4 + 3][kk];
            float bv0 = Bs[kk][tx * 4 + 0];
            float bv1 = Bs[kk][tx * 4 + 1];
            float bv2 = Bs[kk][tx * 4 + 2];
            float bv3 = Bs[kk][tx * 4 + 3];
            acc[0][0] += a0 * bv0; acc[0][1] += a0 * bv1; acc[0][2] += a0 * bv2; acc[0][3] += a0 * bv3;
            acc[1][0] += a1 * bv0; acc[1][1] += a1 * bv1; acc[1][2] += a1 * bv2; acc[1][3] += a1 * bv3;
            acc[2][0] += a2 * bv0; acc[2][1] += a2 * bv1; acc[2][2] += a2 * bv2; acc[2][3] += a2 * bv3;
            acc[3][0] += a3 * bv0; acc[3][1] += a3 * bv1; acc[3][2] += a3 * bv2; acc[3][3] += a3 * bv3;
        }
        __syncthreads();
    }
    #pragma unroll
    for (int i = 0; i < 4; ++i) {
        int m = m0 + ty * 4 + i;
        #pragma unroll
        for (int j = 0; j < 4; ++j) {
            int n = n0 + tx * 4 + j;
            if (n < Ndim) {
                float v = acc[i][j];
                if (bias)      v += bias[n];
                if (fuse_gelu) v = 0.5f * v * (1.f + erff(v * 0.70710678118f));
                if (resid)     v += resid[(size_t)m * Ndim + n];
                out[(size_t)m * Ndim + n] = v;
            }
        }
    }
}

// ------------------------------------------------------------ attention ----
// qkv: [MROWS, 3C] rows = b*T+t; q at col h*D, k at C+h*D, v at 2C+h*D.
// Block = (b, h, 4 query rows). No causal mask (faithful to reference).
__global__ __launch_bounds__(256) void attn_kernel(
    const float* __restrict__ qkv, float* __restrict__ y)
{
    __shared__ float Klds[64][65];    // K or V tile, padded
    __shared__ float qs[4][64];
    __shared__ float s[4][TLEN];      // scores/probs, 16KB

    int blk  = blockIdx.x;            // B*H*(T/4)
    int qblk = blk % (TLEN / 4);
    int bh   = blk / (TLEN / 4);
    int h    = bh % HEADS;
    int b    = bh / HEADS;
    int q0   = qblk * 4;
    int tid  = threadIdx.x;
    int sy   = tid >> 6;              // q row 0..3 (= wave id)
    int sx   = tid & 63;              // lane

    {   // load 4 q rows
        int r = tid / 64, d = tid % 64;
        qs[r][d] = qkv[(size_t)(b * TLEN + q0 + r) * (3 * CDIM) + h * DHEAD + d];
    }
    const float scale = 0.125f;       // 1/sqrt(64)

    // ---- scores: s[r][kt] = q[r] . K[kt] * scale
    for (int kt0 = 0; kt0 < TLEN; kt0 += 64) {
        __syncthreads();
        #pragma unroll
        for (int i = 0; i < 4; ++i) {            // 1024 float4s / 256 threads
            int e  = tid + i * 256;
            int r  = e / 16, c4 = e % 16;
            const float* src = qkv + (size_t)(b * TLEN + kt0 + r) * (3 * CDIM)
                               + CDIM + h * DHEAD + c4 * 4;
            float4 kv = *(const float4*)src;
            Klds[r][c4 * 4 + 0] = kv.x;
            Klds[r][c4 * 4 + 1] = kv.y;
            Klds[r][c4 * 4 + 2] = kv.z;
            Klds[r][c4 * 4 + 3] = kv.w;
        }
        __syncthreads();
        float acc = 0.f;
        #pragma unroll
        for (int d = 0; d < 64; ++d) acc += qs[sy][d] * Klds[sx][d];
        s[sy][kt0 + sx] = acc * scale;
    }
    __syncthreads();

    // ---- softmax per row (wave sy owns row sy)
    float m = -1e30f;
    for (int i = sx; i < TLEN; i += 64) m = fmaxf(m, s[sy][i]);
    #pragma unroll
    for (int o = 1; o < 64; o <<= 1) m = fmaxf(m, __shfl_xor(m, o));
    float sum = 0.f;
    for (int i = sx; i < TLEN; i += 64) {
        float p = expf(s[sy][i] - m);
        s[sy][i] = p;
        sum += p;
    }
    #pragma unroll
    for (int o = 1; o < 64; o <<= 1) sum += __shfl_xor(sum, o);
    float inv = 1.f / sum;

    // ---- y[r][d] = sum_k p[r][k] * V[k][d]   (thread: r=sy, d=sx)
    float acc = 0.f;
    for (int kt0 = 0; kt0 < TLEN; kt0 += 64) {
        __syncthreads();
        #pragma unroll
        for (int i = 0; i < 4; ++i) {
            int e  = tid + i * 256;
            int r  = e / 16, c4 = e % 16;
            const float* src = qkv + (size_t)(b * TLEN + kt0 + r) * (3 * CDIM)
                               + 2 * CDIM + h * DHEAD + c4 * 4;
            float4 vv = *(const float4*)src;
            Klds[r][c4 * 4 + 0] = vv.x;
            Klds[r][c4 * 4 + 1] = vv.y;
            Klds[r][c4 * 4 + 2] = vv.z;
            Klds[r][c4 * 4 + 3] = vv.w;
        }
        __syncthreads();
        #pragma unroll
        for (int k = 0; k < 64; ++k) acc += s[sy][kt0 + k] * Klds[k][sx];
    }
    y[(size_t)(b * TLEN + q0 + sy) * CDIM + h * DHEAD + sx] = acc * inv;
}

// --------------------------------------------------------------- launch ----
extern "C" void kernel_launch(void* const* d_in, const int* in_sizes, int n_in,
                              void* d_out, int out_size, void* d_ws, size_t ws_size,
                              hipStream_t stream)
{
    const int*   idx         = (const int*)  d_in[0];
    const float* wte         = (const float*)d_in[1];
    const float* wpe         = (const float*)d_in[2];
    const float* ln1_w       = (const float*)d_in[3];
    const float* ln1_b       = (const float*)d_in[4];
    const float* qkv_w       = (const float*)d_in[5];
    const float* qkv_b       = (const float*)d_in[6];
    const float* attn_proj_w = (const float*)d_in[7];
    const float* attn_proj_b = (const float*)d_in[8];
    const float* ln2_w       = (const float*)d_in[9];
    const float* ln2_b       = (const float*)d_in[10];
    const float* fc_w        = (const float*)d_in[11];
    const float* fc_b        = (const float*)d_in[12];
    const float* fc2_w       = (const float*)d_in[13];
    const float* fc2_b       = (const float*)d_in[14];
    const float* lnf_w       = (const float*)d_in[15];
    const float* lnf_b       = (const float*)d_in[16];
    const float* lm_w        = (const float*)d_in[17];
    float* logits = (float*)d_out;

    float* x    = (float*)d_ws;            // [2048, 768]
    float* h    = x    + (size_t)MROWS * CDIM;
    float* qkvb = h    + (size_t)MROWS * CDIM;        // [2048, 2304]
    float* yb   = qkvb + (size_t)MROWS * 3 * CDIM;    // [2048, 768]
    float* h4   = yb   + (size_t)MROWS * CDIM;        // [2048, 3072]

    embed_kernel<<<(MROWS * CDIM / 4 + 255) / 256, 256, 0, stream>>>(idx, wte, wpe, x);

    for (int l = 0; l < LAYERS; ++l) {
        layernorm_kernel<<<MROWS, 256, 0, stream>>>(x, ln1_w + l * CDIM, ln1_b + l * CDIM, h);

        gemm_kernel<<<dim3(3 * CDIM / BN, MROWS / BM), 256, 0, stream>>>(
            h, qkv_w + (size_t)l * CDIM * 3 * CDIM, qkv_b + (size_t)l * 3 * CDIM,
            nullptr, qkvb, MROWS, 3 * CDIM, CDIM, 0);

        attn_kernel<<<BSZ * HEADS * (TLEN / 4), 256, 0, stream>>>(qkvb, yb);

        gemm_kernel<<<dim3(CDIM / BN, MROWS / BM), 256, 0, stream>>>(
            yb, attn_proj_w + (size_t)l * CDIM * CDIM, attn_proj_b + (size_t)l * CDIM,
            x, x, MROWS, CDIM, CDIM, 0);

        layernorm_kernel<<<MROWS, 256, 0, stream>>>(x, ln2_w + l * CDIM, ln2_b + l * CDIM, h);

        gemm_kernel<<<dim3(4 * CDIM / BN, MROWS / BM), 256, 0, stream>>>(
            h, fc_w + (size_t)l * CDIM * 4 * CDIM, fc_b + (size_t)l * 4 * CDIM,
            nullptr, h4, MROWS, 4 * CDIM, CDIM, 1 /*gelu*/);

        gemm_kernel<<<dim3(CDIM / BN, MROWS / BM), 256, 0, stream>>>(
            h4, fc2_w + (size_t)l * 4 * CDIM * CDIM, fc2_b + (size_t)l * CDIM,
            x, x, MROWS, CDIM, 4 * CDIM, 0);
    }

    layernorm_kernel<<<MROWS, 256, 0, stream>>>(x, lnf_w, lnf_b, h);

    gemm_kernel<<<dim3((NV + BN - 1) / BN, MROWS / BM), 256, 0, stream>>>(
        h, lm_w, nullptr, nullptr, logits, MROWS, NV, CDIM, 0);
}

// Round 2
// 4745.991 us; speedup vs baseline: 3.5950x; 3.5950x over previous
//
#include <hip/hip_runtime.h>
#include <math.h>

// GPT-2 small forward, bf16 MFMA. B=2 T=1024 C=768 H=12 D=64 L=12 V=50257.
#define CDIM 768
#define HEADS 12
#define DHEAD 64
#define LAYERS 12
#define TLEN 1024
#define BSZ 2
#define MROWS (BSZ * TLEN)   // 2048
#define NV 50257
#define NVPAD 50304
#define NBH (BSZ * HEADS)    // 24

typedef unsigned short u16;
typedef float f32x4 __attribute__((ext_vector_type(4)));
typedef short bf16x8 __attribute__((ext_vector_type(8)));

__device__ __forceinline__ u16 f2bf(float f) {
    union { float f; unsigned int u; } v; v.f = f;
    unsigned int u = v.u;
    return (u16)((u + 0x7fffu + ((u >> 16) & 1u)) >> 16);
}

__device__ __forceinline__ void gload16(const void* g, void* l) {
    __builtin_amdgcn_global_load_lds(
        (const __attribute__((address_space(1))) void*)g,
        (__attribute__((address_space(3))) void*)l, 16, 0, 0);
}

// ---------------------------------------------------------------- embed ----
__global__ __launch_bounds__(256) void embed_kernel(
    const int* __restrict__ idx, const float* __restrict__ wte,
    const float* __restrict__ wpe, float* __restrict__ x)
{
    int i = blockIdx.x * 256 + threadIdx.x;
    int total = MROWS * CDIM / 4;
    if (i >= total) return;
    int row = i / (CDIM / 4);
    int c4  = i % (CDIM / 4);
    int t   = row % TLEN;
    int tok = idx[row];
    float4 a = ((const float4*)(wte + (size_t)tok * CDIM))[c4];
    float4 b = ((const float4*)(wpe + (size_t)t   * CDIM))[c4];
    float4 o;
    o.x = a.x + b.x; o.y = a.y + b.y; o.z = a.z + b.z; o.w = a.w + b.w;
    ((float4*)(x + (size_t)row * CDIM))[c4] = o;
}

// ------------------------------------------------------------ layernorm ----
// fp32 in -> bf16 out. one block (256 threads) per row.
__global__ __launch_bounds__(256) void layernorm_kernel(
    const float* __restrict__ in, const float* __restrict__ w,
    const float* __restrict__ b, u16* __restrict__ out)
{
    int row = blockIdx.x;
    int tid = threadIdx.x;
    const float* xr = in + (size_t)row * CDIM;
    float v0 = xr[tid], v1 = xr[tid + 256], v2 = xr[tid + 512];
    float s  = v0 + v1 + v2;
    float ss = v0 * v0 + v1 * v1 + v2 * v2;
    #pragma unroll
    for (int o = 1; o < 64; o <<= 1) {
        s  += __shfl_xor(s,  o);
        ss += __shfl_xor(ss, o);
    }
    __shared__ float red[10];
    int wave = tid >> 6, lane = tid & 63;
    if (lane == 0) { red[wave] = s; red[4 + wave] = ss; }
    __syncthreads();
    if (tid == 0) {
        float S  = red[0] + red[1] + red[2] + red[3];
        float SS = red[4] + red[5] + red[6] + red[7];
        float mu  = S / CDIM;
        float var = SS / CDIM - mu * mu;
        red[8] = mu;
        red[9] = rsqrtf(var + 1e-5f);
    }
    __syncthreads();
    float mu = red[8], rstd = red[9];
    u16* orow = out + (size_t)row * CDIM;
    orow[tid]       = f2bf((v0 - mu) * rstd * w[tid]       + b[tid]);
    orow[tid + 256] = f2bf((v1 - mu) * rstd * w[tid + 256] + b[tid + 256]);
    orow[tid + 512] = f2bf((v2 - mu) * rstd * w[tid + 512] + b[tid + 512]);
}

// --------------------------------------------------- cast + transpose -----
// in fp32 [K][Nin] row-major -> out bf16 [Npad][K] (rows n>=Nin zero-filled)
// grid (Npad/64, K/64)
__global__ __launch_bounds__(256) void castT_kernel(
    const float* __restrict__ in, u16* __restrict__ out, int K, int Nin)
{
    __shared__ float t[64][65];
    int n0 = blockIdx.x * 64, k0 = blockIdx.y * 64;
    int tid = threadIdx.x;
    int a = tid & 63, q = tid >> 6;     // a: 0..63, q: 0..3
    #pragma unroll
    for (int i = 0; i < 16; ++i) {
        int kk = q + i * 4, nn = a;
        int n = n0 + nn;
        t[kk][nn] = (n < Nin) ? in[(size_t)(k0 + kk) * Nin + n] : 0.f;
    }
    __syncthreads();
    #pragma unroll
    for (int i = 0; i < 16; ++i) {
        int nn = q + i * 4, kk = a;
        out[(size_t)(n0 + nn) * K + k0 + kk] = f2bf(t[kk][nn]);
    }
}

// ------------------------------------------------------- V transpose ------
// qkvb bf16 [2048][2304] (v at col 1536+h*64) -> vT bf16 [24][128][1024]
// (rows d=64..127 pre-zeroed by memset). grid (TLEN/64, NBH)
__global__ __launch_bounds__(256) void vtrans_kernel(
    const u16* __restrict__ qkvb, u16* __restrict__ vT)
{
    __shared__ u16 t[64 * 65];
    int z = blockIdx.y;
    int bb = z / HEADS, hh = z % HEADS;
    int t0 = blockIdx.x * 64;
    int tid = threadIdx.x;
    int g8 = tid & 7, gi = tid >> 3;    // g8: 0..7, gi: 0..31
    #pragma unroll
    for (int i = 0; i < 2; ++i) {
        int tt = gi + i * 32;
        int d0 = g8 * 8;
        const u16* src = qkvb + (size_t)(bb * TLEN + t0 + tt) * (3 * CDIM)
                         + 2 * CDIM + hh * DHEAD + d0;
        u16 tmp[8];
        *(uint4*)tmp = *(const uint4*)src;
        #pragma unroll
        for (int j = 0; j < 8; ++j) t[(d0 + j) * 65 + tt] = tmp[j];
    }
    __syncthreads();
    #pragma unroll
    for (int i = 0; i < 2; ++i) {
        int dd = gi + i * 32;
        int tc = g8 * 8;
        u16 tmp[8];
        #pragma unroll
        for (int j = 0; j < 8; ++j) tmp[j] = t[dd * 65 + tc + j];
        *(uint4*)(vT + (size_t)z * 128 * TLEN + (size_t)dd * TLEN + t0 + tc) = *(uint4*)tmp;
    }
}

// -------------------------------------------------------------- softmax ---
// S fp32 [rows][1024] -> P bf16 [rows][1024]; one block per row.
__global__ __launch_bounds__(256) void softmax_kernel(
    const float* __restrict__ S, u16* __restrict__ P)
{
    size_t base = (size_t)blockIdx.x * TLEN;
    int tid = threadIdx.x;
    float v[4];
    float mx = -1e30f;
    #pragma unroll
    for (int i = 0; i < 4; ++i) { v[i] = S[base + tid + i * 256]; mx = fmaxf(mx, v[i]); }
    #pragma unroll
    for (int o = 1; o < 64; o <<= 1) mx = fmaxf(mx, __shfl_xor(mx, o));
    __shared__ float red[8];
    int wv = tid >> 6, ln = tid & 63;
    if (ln == 0) red[wv] = mx;
    __syncthreads();
    mx = fmaxf(fmaxf(red[0], red[1]), fmaxf(red[2], red[3]));
    float sum = 0.f;
    #pragma unroll
    for (int i = 0; i < 4; ++i) { v[i] = expf(v[i] - mx); sum += v[i]; }
    #pragma unroll
    for (int o = 1; o < 64; o <<= 1) sum += __shfl_xor(sum, o);
    if (ln == 0) red[4 + wv] = sum;
    __syncthreads();
    float inv = 1.f / (red[4] + red[5] + red[6] + red[7]);
    #pragma unroll
    for (int i = 0; i < 4; ++i) P[base + tid + i * 256] = f2bf(v[i] * inv);
}

// ------------------------------------------------------------ MFMA GEMM ---
// C[M,N] = A[M,K] * B^T-layout[Npad,K] (both bf16, k-contiguous rows).
// 128x128 tile, BK=64, 256 thr = 4 waves (2x2), 4x4 16x16 frags per wave.
// Batched via blockIdx.z: off = (z/zdiv)*s1 + (z%zdiv)*s2 per operand.
// flags: bit0 = fp32 out (else bf16), bit1 = exact gelu. resid: fp32 += .
__global__ __launch_bounds__(256) void gemm_bf16(
    const u16* __restrict__ A, int lda, long zA1, long zA2,
    const u16* __restrict__ B, int ldb, long zB1, long zB2,
    void* __restrict__ C, int ldc, long zC1, long zC2,
    const float* __restrict__ bias, const float* __restrict__ resid,
    int N, int K, int zdiv, float scale, int flags)
{
    __shared__ u16 As[128 * 64];
    __shared__ u16 Bs[128 * 64];
    int z = blockIdx.z;
    const u16* Ab = A + (size_t)((z / zdiv) * zA1 + (z % zdiv) * zA2);
    const u16* Bb = B + (size_t)((z / zdiv) * zB1 + (z % zdiv) * zB2);
    size_t zc = (size_t)((z / zdiv) * zC1 + (z % zdiv) * zC2);
    int m0 = blockIdx.y * 128, n0 = blockIdx.x * 128;
    int tid = threadIdx.x;
    int w = tid >> 6, l = tid & 63;
    int wr = w >> 1, wc = w & 1;
    int lo = l & 15, hi = l >> 4;
    int srow = l >> 3;            // 0..7
    int scol = (l & 7) * 8;       // 0,8,..,56

    f32x4 acc[4][4];
    #pragma unroll
    for (int m = 0; m < 4; ++m)
        #pragma unroll
        for (int n = 0; n < 4; ++n)
            #pragma unroll
            for (int r = 0; r < 4; ++r) acc[m][n][r] = 0.f;

    for (int k0 = 0; k0 < K; k0 += 64) {
        #pragma unroll
        for (int j = 0; j < 4; ++j) {
            int blkrow = (w * 4 + j) * 8 + srow;
            gload16(Ab + (size_t)(m0 + blkrow) * lda + k0 + scol, As + (w * 4 + j) * 512);
            gload16(Bb + (size_t)(n0 + blkrow) * ldb + k0 + scol, Bs + (w * 4 + j) * 512);
        }
        __syncthreads();
        #pragma unroll
        for (int ks = 0; ks < 2; ++ks) {
            bf16x8 af[4], bfr[4];
            #pragma unroll
            for (int m = 0; m < 4; ++m)
                af[m] = *(const bf16x8*)(As + (wr * 64 + m * 16 + lo) * 64 + ks * 32 + hi * 8);
            #pragma unroll
            for (int n = 0; n < 4; ++n)
                bfr[n] = *(const bf16x8*)(Bs + (wc * 64 + n * 16 + lo) * 64 + ks * 32 + hi * 8);
            #pragma unroll
            for (int m = 0; m < 4; ++m)
                #pragma unroll
                for (int n = 0; n < 4; ++n)
                    acc[m][n] = __builtin_amdgcn_mfma_f32_16x16x32_bf16(
                        af[m], bfr[n], acc[m][n], 0, 0, 0);
        }
        __syncthreads();
    }

    float* Cf = (float*)C + zc;
    u16*   Cb = (u16*)C + zc;
    #pragma unroll
    for (int n = 0; n < 4; ++n) {
        int col = n0 + wc * 64 + n * 16 + lo;
        if (col >= N) continue;
        float bv = bias ? bias[col] : 0.f;
        #pragma unroll
        for (int m = 0; m < 4; ++m) {
            #pragma unroll
            for (int r = 0; r < 4; ++r) {
                int row = m0 + wr * 64 + m * 16 + hi * 4 + r;
                float v = acc[m][n][r] * scale + bv;
                if (flags & 2) v = 0.5f * v * (1.f + erff(v * 0.70710678118654752f));
                if (resid) v += resid[(size_t)row * ldc + col];
                if (flags & 1) Cf[(size_t)row * ldc + col] = v;
                else           Cb[(size_t)row * ldc + col] = f2bf(v);
            }
        }
    }
}

// --------------------------------------------------------------- launch ----
extern "C" void kernel_launch(void* const* d_in, const int* in_sizes, int n_in,
                              void* d_out, int out_size, void* d_ws, size_t ws_size,
                              hipStream_t stream)
{
    const int*   idx         = (const int*)  d_in[0];
    const float* wte         = (const float*)d_in[1];
    const float* wpe         = (const float*)d_in[2];
    const float* ln1_w       = (const float*)d_in[3];
    const float* ln1_b       = (const float*)d_in[4];
    const float* qkv_w       = (const float*)d_in[5];
    const float* qkv_b       = (const float*)d_in[6];
    const float* attn_proj_w = (const float*)d_in[7];
    const float* attn_proj_b = (const float*)d_in[8];
    const float* ln2_w       = (const float*)d_in[9];
    const float* ln2_b       = (const float*)d_in[10];
    const float* fc_w        = (const float*)d_in[11];
    const float* fc_b        = (const float*)d_in[12];
    const float* fc2_w       = (const float*)d_in[13];
    const float* fc2_b       = (const float*)d_in[14];
    const float* lnf_w       = (const float*)d_in[15];
    const float* lnf_b       = (const float*)d_in[16];
    const float* lm_w        = (const float*)d_in[17];
    float* logits = (float*)d_out;

    // ---- ws carve (~123 MB) ----
    char* W = (char*)d_ws;
    float* x   = (float*)W;  W += (size_t)MROWS * CDIM * 4;        // 6.3 MB
    u16* h     = (u16*)W;    W += (size_t)MROWS * CDIM * 2;        // 3.1 MB
    u16* qkvb  = (u16*)W;    W += (size_t)MROWS * 3 * CDIM * 2;    // 9.4 MB
    u16* y     = (u16*)W;    W += (size_t)MROWS * CDIM * 2;        // 3.1 MB
    u16* h4    = (u16*)W;    W += (size_t)MROWS * 4 * CDIM * 2;    // 12.6 MB
    u16* vT    = (u16*)W;    W += (size_t)NBH * 128 * TLEN * 2;    // 6.3 MB
    u16* WT    = (u16*)W;    W += (size_t)4 * CDIM * CDIM * 2;     // 4.7 MB (reused)
    u16* lmT   = (u16*)W;    W += (size_t)NVPAD * CDIM * 2;        // 77.3 MB

    // ---- attention scratch lives in d_out (dead until final logits GEMM) --
    float* S = (float*)d_out;                                   // 100.7 MB
    u16*   P = (u16*)((char*)d_out + (size_t)NBH * TLEN * TLEN * 4); // 50.3 MB

    embed_kernel<<<(MROWS * CDIM / 4 + 255) / 256, 256, 0, stream>>>(idx, wte, wpe, x);

    for (int l = 0; l < LAYERS; ++l) {
        // qkv weight cast+T, ln1, qkv GEMM -> qkvb (bf16, +bias)
        castT_kernel<<<dim3(3 * CDIM / 64, CDIM / 64), 256, 0, stream>>>(
            qkv_w + (size_t)l * CDIM * 3 * CDIM, WT, CDIM, 3 * CDIM);
        layernorm_kernel<<<MROWS, 256, 0, stream>>>(x, ln1_w + l * CDIM, ln1_b + l * CDIM, h);
        gemm_bf16<<<dim3(3 * CDIM / 128, MROWS / 128, 1), 256, 0, stream>>>(
            h, CDIM, 0, 0, WT, CDIM, 0, 0, qkvb, 3 * CDIM, 0, 0,
            qkv_b + (size_t)l * 3 * CDIM, nullptr, 3 * CDIM, CDIM, 1, 1.f, 0);

        // V^T (padded to 128 d-rows, zero tail)
        hipMemsetAsync(vT, 0, (size_t)NBH * 128 * TLEN * 2, stream);
        vtrans_kernel<<<dim3(TLEN / 64, NBH), 256, 0, stream>>>(qkvb, vT);

        // S = Q K^T * 0.125  (batched over b,h; fp32 into d_out scratch)
        gemm_bf16<<<dim3(TLEN / 128, TLEN / 128, NBH), 256, 0, stream>>>(
            qkvb, 3 * CDIM, (long)TLEN * 3 * CDIM, DHEAD,
            qkvb + CDIM, 3 * CDIM, (long)TLEN * 3 * CDIM, DHEAD,
            S, TLEN, (long)HEADS * TLEN * TLEN, (long)TLEN * TLEN,
            nullptr, nullptr, TLEN, DHEAD, HEADS, 0.125f, 1);

        softmax_kernel<<<NBH * TLEN, 256, 0, stream>>>(S, P);

        castT_kernel<<<dim3(CDIM / 64, CDIM / 64), 256, 0, stream>>>(
            attn_proj_w + (size_t)l * CDIM * CDIM, WT, CDIM, CDIM);

        // O = P V  -> y (bf16)
        gemm_bf16<<<dim3(1, TLEN / 128, NBH), 256, 0, stream>>>(
            P, TLEN, (long)HEADS * TLEN * TLEN, (long)TLEN * TLEN,
            vT, TLEN, (long)HEADS * 128 * TLEN, (long)128 * TLEN,
            y, CDIM, (long)TLEN * CDIM, DHEAD,
            nullptr, nullptr, DHEAD, TLEN, HEADS, 1.f, 0);

        // x += y @ proj + b   (fp32 resid)
        gemm_bf16<<<dim3(CDIM / 128, MROWS / 128, 1), 256, 0, stream>>>(
            y, CDIM, 0, 0, WT, CDIM, 0, 0, x, CDIM, 0, 0,
            attn_proj_b + (size_t)l * CDIM, x, CDIM, CDIM, 1, 1.f, 1);

        // MLP
        layernorm_kernel<<<MROWS, 256, 0, stream>>>(x, ln2_w + l * CDIM, ln2_b + l * CDIM, h);
        castT_kernel<<<dim3(4 * CDIM / 64, CDIM / 64), 256, 0, stream>>>(
            fc_w + (size_t)l * CDIM * 4 * CDIM, WT, CDIM, 4 * CDIM);
        gemm_bf16<<<dim3(4 * CDIM / 128, MROWS / 128, 1), 256, 0, stream>>>(
            h, CDIM, 0, 0, WT, CDIM, 0, 0, h4, 4 * CDIM, 0, 0,
            fc_b + (size_t)l * 4 * CDIM, nullptr, 4 * CDIM, CDIM, 1, 1.f, 2 /*gelu*/);
        castT_kernel<<<dim3(CDIM / 64, 4 * CDIM / 64), 256, 0, stream>>>(
            fc2_w + (size_t)l * 4 * CDIM * CDIM, WT, 4 * CDIM, CDIM);
        gemm_bf16<<<dim3(CDIM / 128, MROWS / 128, 1), 256, 0, stream>>>(
            h4, 4 * CDIM, 0, 0, WT, 4 * CDIM, 0, 0, x, CDIM, 0, 0,
            fc2_b + (size_t)l * CDIM, x, CDIM, 4 * CDIM, 1, 1.f, 1);
    }

    layernorm_kernel<<<MROWS, 256, 0, stream>>>(x, lnf_w, lnf_b, h);

    castT_kernel<<<dim3(NVPAD / 64, CDIM / 64), 256, 0, stream>>>(lm_w, lmT, CDIM, NV);
    gemm_bf16<<<dim3(NVPAD / 128, MROWS / 128, 1), 256, 0, stream>>>(
        h, CDIM, 0, 0, lmT, CDIM, 0, 0, logits, NV, 0, 0,
        nullptr, nullptr, NV, CDIM, 1, 1.f, 1);
}